// Round 1
// baseline (647.621 us; speedup 1.0000x reference)
//
#include <hip/hip_runtime.h>
#include <math.h>

#define PI_F 3.14159265358979323846f

// ---------------------------------------------------------------------------
// Rot coefficient precompute: 72 gates (6 layers x 12 wires), 8 floats each.
// Rot = RZ(om) RY(th) RZ(phi) per PennyLane:
//   u00 = e^{-i(phi+om)/2} cos(th/2)   u01 = -e^{+i(phi-om)/2} sin(th/2)
//   u10 = e^{-i(phi-om)/2} sin(th/2)   u11 = e^{+i(phi+om)/2} cos(th/2)
// ---------------------------------------------------------------------------
__global__ void rot_coef_kernel(const float* __restrict__ weights,
                                float* __restrict__ coef) {
    int g = blockIdx.x * blockDim.x + threadIdx.x;
    if (g < 72) {
        float phi = weights[g * 3 + 0];
        float th  = weights[g * 3 + 1];
        float om  = weights[g * 3 + 2];
        float hs = 0.5f * (phi + om), hd = 0.5f * (phi - om), ht = 0.5f * th;
        float ct = cosf(ht), st = sinf(ht);
        float cs = cosf(hs), ss = sinf(hs);
        float cd = cosf(hd), sd = sinf(hd);
        float* c = coef + g * 8;
        c[0] = cs * ct;  c[1] = -ss * ct;   // u00
        c[2] = -cd * st; c[3] = -sd * st;   // u01
        c[4] = cd * st;  c[5] = -sd * st;   // u10
        c[6] = cs * ct;  c[7] = ss * ct;    // u11
    }
}

struct U2 { float r00, i00, r01, i01, r10, i10, r11, i11; };

// Layout: block = 256 threads, one batch element per block.
// State index i (12 bits), amp i held by thread t = i>>4, slot k = i&15.
//   bits 0..3  = k (in-register)     -> wires 11..8
//   bits 4..9  = lane bits 0..5      -> wires 7..2
//   bits 10..11= wave bits (t>>6)    -> wires 1..0
// Gate on wire w acts on bit b = 11-w.

template <int B>
__device__ __forceinline__ void apply_rot_bit(float (&re)[16], float (&im)[16],
                                              const U2& u, int t, float2* xch) {
    if constexpr (B < 4) {
        constexpr int m = 1 << B;
        #pragma unroll
        for (int k0 = 0; k0 < 16; ++k0) {
            if ((k0 & m) == 0) {
                const int k1 = k0 | m;
                float a0r = re[k0], a0i = im[k0], a1r = re[k1], a1i = im[k1];
                re[k0] = u.r00 * a0r - u.i00 * a0i + u.r01 * a1r - u.i01 * a1i;
                im[k0] = u.r00 * a0i + u.i00 * a0r + u.r01 * a1i + u.i01 * a1r;
                re[k1] = u.r10 * a0r - u.i10 * a0i + u.r11 * a1r - u.i11 * a1i;
                im[k1] = u.r10 * a0i + u.i10 * a0r + u.r11 * a1i + u.i11 * a1r;
            }
        }
    } else if constexpr (B < 10) {
        constexpr int lm = 1 << (B - 4);
        const int mybit = (t >> (B - 4)) & 1;
        const float uar = mybit ? u.r11 : u.r00;
        const float uai = mybit ? u.i11 : u.i00;
        const float ubr = mybit ? u.r10 : u.r01;
        const float ubi = mybit ? u.i10 : u.i01;
        #pragma unroll
        for (int k = 0; k < 16; ++k) {
            float pr = __shfl_xor(re[k], lm, 64);
            float pi = __shfl_xor(im[k], lm, 64);
            float r0 = re[k], i0 = im[k];
            re[k] = uar * r0 - uai * i0 + ubr * pr - ubi * pi;
            im[k] = uar * i0 + uai * r0 + ubr * pi + ubi * pr;
        }
    } else {
        constexpr int tmsk = 64 << (B - 10);
        const int mybit = (t >> (B - 4)) & 1;
        const float uar = mybit ? u.r11 : u.r00;
        const float uai = mybit ? u.i11 : u.i00;
        const float ubr = mybit ? u.r10 : u.r01;
        const float ubi = mybit ? u.i10 : u.i01;
        const int sw = t & 15;  // XOR swizzle -> b64 accesses hit the 4-cyc floor
        __syncthreads();
        #pragma unroll
        for (int k = 0; k < 16; ++k)
            xch[t * 16 + (k ^ sw)] = make_float2(re[k], im[k]);
        __syncthreads();
        const int pt = t ^ tmsk;  // pt&15 == t&15
        #pragma unroll
        for (int k = 0; k < 16; ++k) {
            float2 p = xch[pt * 16 + (k ^ sw)];
            float r0 = re[k], i0 = im[k];
            re[k] = uar * r0 - uai * i0 + ubr * p.x - ubi * p.y;
            im[k] = uar * i0 + uai * r0 + ubr * p.y + ubi * p.x;
        }
    }
}

template <int CB, int TB>
__device__ __forceinline__ void apply_cnot_bits(float (&re)[16], float (&im)[16],
                                                int t, float2* xch) {
    const int lane = t & 63;
    if constexpr (CB < 4 && TB < 4) {
        // pure static in-register permutation (free after unroll)
        constexpr int cm = 1 << CB, tm = 1 << TB;
        #pragma unroll
        for (int k0 = 0; k0 < 16; ++k0) {
            if ((k0 & cm) && !(k0 & tm)) {
                const int k1 = k0 | tm;
                float tr = re[k0]; re[k0] = re[k1]; re[k1] = tr;
                float ti = im[k0]; im[k0] = im[k1]; im[k1] = ti;
            }
        }
    } else if constexpr (CB < 4 && TB < 10) {
        // control local, target lane: unconditional cross-lane swap for k with ctrl=1
        constexpr int cm = 1 << CB, lm = 1 << (TB - 4);
        #pragma unroll
        for (int k = 0; k < 16; ++k) {
            if (k & cm) {
                re[k] = __shfl_xor(re[k], lm, 64);
                im[k] = __shfl_xor(im[k], lm, 64);
            }
        }
    } else if constexpr (CB < 4) {
        // control local, target wave bit: LDS exchange of the ctrl=1 half
        constexpr int cm = 1 << CB, tmsk = 64 << (TB - 10);
        const int sw = t & 15;
        __syncthreads();
        #pragma unroll
        for (int k = 0; k < 16; ++k)
            if (k & cm) xch[t * 16 + (k ^ sw)] = make_float2(re[k], im[k]);
        __syncthreads();
        const int pt = t ^ tmsk;
        #pragma unroll
        for (int k = 0; k < 16; ++k) {
            if (k & cm) {
                float2 p = xch[pt * 16 + (k ^ sw)];
                re[k] = p.x; im[k] = p.y;
            }
        }
    } else {
        // control is a lane/wave bit -> uniform per-thread condition
        const int cond = (t >> (CB - 4)) & 1;
        if constexpr (TB < 4) {
            constexpr int tm = 1 << TB;
            #pragma unroll
            for (int k0 = 0; k0 < 16; ++k0) {
                if (!(k0 & tm)) {
                    const int k1 = k0 | tm;
                    float r0 = re[k0], i0 = im[k0], r1 = re[k1], i1 = im[k1];
                    re[k0] = cond ? r1 : r0; im[k0] = cond ? i1 : i0;
                    re[k1] = cond ? r0 : r1; im[k1] = cond ? i0 : i1;
                }
            }
        } else if constexpr (TB < 10) {
            constexpr int lm = 1 << (TB - 4);
            const int src = cond ? (lane ^ lm) : lane;
            #pragma unroll
            for (int k = 0; k < 16; ++k) {
                re[k] = __shfl(re[k], src, 64);
                im[k] = __shfl(im[k], src, 64);
            }
        } else {
            // target wave bit; note: partner thread has the SAME cond (CB != TB)
            constexpr int tmsk = 64 << (TB - 10);
            const int sw = t & 15;
            __syncthreads();
            if (cond) {
                #pragma unroll
                for (int k = 0; k < 16; ++k)
                    xch[t * 16 + (k ^ sw)] = make_float2(re[k], im[k]);
            }
            __syncthreads();
            const int pt = t ^ tmsk;
            if (cond) {
                #pragma unroll
                for (int k = 0; k < 16; ++k) {
                    float2 p = xch[pt * 16 + (k ^ sw)];
                    re[k] = p.x; im[k] = p.y;
                }
            }
        }
    }
}

template <int W>
__device__ __forceinline__ void layer_rots(float (&re)[16], float (&im)[16],
                                           const float* __restrict__ coef,
                                           const float* __restrict__ wl,
                                           int t, float2* xch) {
    if constexpr (W < 12) {
        U2 u;
        if (coef) {
            const float* c = coef + W * 8;
            u.r00 = c[0]; u.i00 = c[1]; u.r01 = c[2]; u.i01 = c[3];
            u.r10 = c[4]; u.i10 = c[5]; u.r11 = c[6]; u.i11 = c[7];
        } else {
            float phi = wl[W * 3 + 0], th = wl[W * 3 + 1], om = wl[W * 3 + 2];
            float hs = 0.5f * (phi + om), hd = 0.5f * (phi - om), ht = 0.5f * th;
            float st, ct, ss, cs, sd, cd;
            __sincosf(ht, &st, &ct);
            __sincosf(hs, &ss, &cs);
            __sincosf(hd, &sd, &cd);
            u.r00 = cs * ct;  u.i00 = -ss * ct;
            u.r01 = -cd * st; u.i01 = -sd * st;
            u.r10 = cd * st;  u.i10 = -sd * st;
            u.r11 = cs * ct;  u.i11 = ss * ct;
        }
        apply_rot_bit<11 - W>(re, im, u, t, xch);
        layer_rots<W + 1>(re, im, coef, wl, t, xch);
    }
}

template <int R, int W>
__device__ __forceinline__ void layer_cnots(float (&re)[16], float (&im)[16],
                                            int t, float2* xch) {
    if constexpr (W < 12) {
        apply_cnot_bits<11 - W, 11 - ((W + R) % 12)>(re, im, t, xch);
        layer_cnots<R, W + 1>(re, im, t, xch);
    }
}

__global__ __launch_bounds__(256) void qvl_main(
    const float* __restrict__ v,        // (B, 512)
    const float* __restrict__ Wc,       // (12, 512)
    const float* __restrict__ bc,       // (12,)
    const float* __restrict__ weights,  // (6, 12, 3)
    const float* __restrict__ coef,     // (72, 8) or null
    float* __restrict__ out)            // (B, 12)
{
    __shared__ float2 xch[4096];   // 32 KB cross-wave exchange buffer
    __shared__ float red[12][4];

    const int t    = threadIdx.x;
    const int lane = t & 63;
    const int wave = t >> 6;
    const int b    = blockIdx.x;

    // ---- x = tanh(v @ Wc^T + bc) * pi -------------------------------------
    {
        const int base = wave * 128 + lane * 2;
        const float2 vv = *reinterpret_cast<const float2*>(v + b * 512 + base);
        #pragma unroll
        for (int w = 0; w < 12; ++w) {
            const float2 ww = *reinterpret_cast<const float2*>(Wc + w * 512 + base);
            float p = vv.x * ww.x + vv.y * ww.y;
            #pragma unroll
            for (int s = 1; s < 64; s <<= 1) p += __shfl_xor(p, s, 64);
            if (lane == 0) red[w][wave] = p;
        }
    }
    __syncthreads();
    float ce[12], se[12];
    #pragma unroll
    for (int w = 0; w < 12; ++w) {
        float x = tanhf(red[w][0] + red[w][1] + red[w][2] + red[w][3] + bc[w]) * PI_F;
        float h = 0.5f * x;
        se[w] = sinf(h);
        ce[w] = cosf(h);
    }

    // ---- AngleEmbedding(RY) as a direct product state ----------------------
    // amp[i] = prod_w (bit_{11-w}(i) ? sin(x_w/2) : cos(x_w/2)), im = 0
    float re[16], im[16];
    float fl = 1.0f;
    fl *= (lane & 1)  ? se[7] : ce[7];   // lane bit 0 -> state bit 4 -> wire 7
    fl *= (lane & 2)  ? se[6] : ce[6];
    fl *= (lane & 4)  ? se[5] : ce[5];
    fl *= (lane & 8)  ? se[4] : ce[4];
    fl *= (lane & 16) ? se[3] : ce[3];
    fl *= (lane & 32) ? se[2] : ce[2];
    fl *= (wave & 1)  ? se[1] : ce[1];   // state bit 10 -> wire 1
    fl *= (wave & 2)  ? se[0] : ce[0];   // state bit 11 -> wire 0
    #pragma unroll
    for (int k = 0; k < 16; ++k) {
        float f = ((k & 1) ? se[11] : ce[11]) * ((k & 2) ? se[10] : ce[10]) *
                  ((k & 4) ? se[9]  : ce[9])  * ((k & 8) ? se[8]  : ce[8]);
        re[k] = fl * f;
        im[k] = 0.0f;
    }

    // ---- 6 StronglyEntanglingLayers ----------------------------------------
    #pragma unroll 1
    for (int l = 0; l < 6; ++l) {
        const float* cf = coef ? (coef + l * 96) : (const float*)nullptr;
        layer_rots<0>(re, im, cf, weights + l * 36, t, xch);
        switch (l) {  // r = l + 1 (l % 11 + 1 for l < 11)
            case 0: layer_cnots<1, 0>(re, im, t, xch); break;
            case 1: layer_cnots<2, 0>(re, im, t, xch); break;
            case 2: layer_cnots<3, 0>(re, im, t, xch); break;
            case 3: layer_cnots<4, 0>(re, im, t, xch); break;
            case 4: layer_cnots<5, 0>(re, im, t, xch); break;
            case 5: layer_cnots<6, 0>(re, im, t, xch); break;
        }
    }

    // ---- PauliZ expvals -----------------------------------------------------
    float z[12];
    #pragma unroll
    for (int w = 0; w < 12; ++w) z[w] = 0.0f;
    float tot = 0.0f;
    #pragma unroll
    for (int k = 0; k < 16; ++k) {
        float p = re[k] * re[k] + im[k] * im[k];
        tot += p;
        z[11] += (k & 1) ? -p : p;   // k bit 0 -> wire 11
        z[10] += (k & 2) ? -p : p;
        z[9]  += (k & 4) ? -p : p;
        z[8]  += (k & 8) ? -p : p;
    }
    z[7] = (lane & 1)  ? -tot : tot;
    z[6] = (lane & 2)  ? -tot : tot;
    z[5] = (lane & 4)  ? -tot : tot;
    z[4] = (lane & 8)  ? -tot : tot;
    z[3] = (lane & 16) ? -tot : tot;
    z[2] = (lane & 32) ? -tot : tot;
    z[1] = (t & 64)    ? -tot : tot;   // state bit 10 -> wire 1
    z[0] = (t & 128)   ? -tot : tot;   // state bit 11 -> wire 0
    #pragma unroll
    for (int w = 0; w < 12; ++w) {
        #pragma unroll
        for (int s = 1; s < 64; s <<= 1) z[w] += __shfl_xor(z[w], s, 64);
    }
    __syncthreads();
    if (lane == 0) {
        #pragma unroll
        for (int w = 0; w < 12; ++w) red[w][wave] = z[w];
    }
    __syncthreads();
    if (t < 12)
        out[b * 12 + t] = red[t][0] + red[t][1] + red[t][2] + red[t][3];
}

extern "C" void kernel_launch(void* const* d_in, const int* in_sizes, int n_in,
                              void* d_out, int out_size, void* d_ws, size_t ws_size,
                              hipStream_t stream) {
    (void)n_in; (void)out_size;
    const float* v   = (const float*)d_in[0];
    const float* Wc  = (const float*)d_in[1];
    const float* bc  = (const float*)d_in[2];
    const float* wts = (const float*)d_in[3];
    float* out = (float*)d_out;

    const int B = in_sizes[0] / 512;

    float* coef = nullptr;
    if (d_ws && ws_size >= 72 * 8 * sizeof(float)) {
        coef = (float*)d_ws;
        rot_coef_kernel<<<1, 128, 0, stream>>>(wts, coef);
    }
    qvl_main<<<B, 256, 0, stream>>>(v, Wc, bc, wts, coef, out);
}